// Round 1
// baseline (82673.224 us; speedup 1.0000x reference)
//
#include <hip/hip_runtime.h>

#define T_STEPS 8192
#define HDIM 1024
#define NA 64            // layer-0 workgroups
#define NB 128           // layer-1 workgroups
#define NWG (NA + NB)
#define FSTR 16          // flag stride in ints (64B lines)

// ---------- helpers ----------
__device__ __forceinline__ float dot4(float4 a, float4 b) {
    return a.x * b.x + a.y * b.y + a.z * b.z + a.w * b.w;
}

__device__ __forceinline__ float wred(float v) {
#pragma unroll
    for (int s = 32; s >= 1; s >>= 1) v += __shfl_xor(v, s, 64);
    return v;
}

__device__ __forceinline__ float sigm(float x) { return 1.0f / (1.0f + expf(-x)); }

// Global phase barrier across all NWG workgroups.
// Producer side: plain stores already done by all waves; first __syncthreads drains vmcnt.
// tid0: agent release fence (buffer_wbl2 sc1) then epoch-flag store (sc1).
// wave0 polls all flags with agent-scope relaxed loads (sc1 -> reads L3, not stale L2),
// then acquire fence (buffer_inv) so subsequent plain loads see fresh data.
__device__ __forceinline__ void barrier_phase(int* flags, int* abortf, int target,
                                              int tid, int wv, int lane, int wg) {
    __syncthreads();
    if (tid == 0) {
        __threadfence();
        __hip_atomic_store(flags + wg * FSTR, target, __ATOMIC_RELAXED, __HIP_MEMORY_SCOPE_AGENT);
    }
    if (wv == 0) {
        const int i0 = lane * FSTR;
        const int i1 = (lane + 64) * FSTR;
        const int i2 = (lane + 128) * FSTR;
        long it = 0;
        for (;;) {
            int f0 = __hip_atomic_load(flags + i0, __ATOMIC_RELAXED, __HIP_MEMORY_SCOPE_AGENT);
            int f1 = __hip_atomic_load(flags + i1, __ATOMIC_RELAXED, __HIP_MEMORY_SCOPE_AGENT);
            int f2 = __hip_atomic_load(flags + i2, __ATOMIC_RELAXED, __HIP_MEMORY_SCOPE_AGENT);
            int ab = __hip_atomic_load(abortf, __ATOMIC_RELAXED, __HIP_MEMORY_SCOPE_AGENT);
            int ok = (f0 >= target) && (f1 >= target) && (f2 >= target);
            if (__all(ok || (ab != 0))) break;
            if (++it > 50000000L)   // deadlock safety valve: convert hang -> fast wrong exit
                __hip_atomic_store(abortf, 1, __ATOMIC_RELAXED, __HIP_MEMORY_SCOPE_AGENT);
        }
        __threadfence();
    }
    __syncthreads();
}

// ---------- prologue: u = Wih0*Win, v = Wih0*bin + bih0 + bhh0, b1 = bih1 + bhh1 ----------
__global__ void lstm_prologue(const float* __restrict__ Wih0, const float* __restrict__ Win,
                              const float* __restrict__ bin, const float* __restrict__ bih0,
                              const float* __restrict__ bhh0, const float* __restrict__ bih1,
                              const float* __restrict__ bhh1,
                              float* __restrict__ U, float* __restrict__ V, float* __restrict__ B1) {
    const int wv = threadIdx.x >> 6, lane = threadIdx.x & 63;
    const int r = blockIdx.x * 4 + wv;
    const float4* wp = (const float4*)(Wih0 + (size_t)r * HDIM + lane * 16);
    const float4* xp = (const float4*)(Win + lane * 16);
    const float4* bp = (const float4*)(bin + lane * 16);
    float au = 0.f, av = 0.f;
#pragma unroll
    for (int j = 0; j < 4; ++j) {
        float4 wj = wp[j];
        au += dot4(wj, xp[j]);
        av += dot4(wj, bp[j]);
    }
    au = wred(au);
    av = wred(av);
    if (lane == 0) {
        U[r] = au;
        V[r] = av + bih0[r] + bhh0[r];
        B1[r] = bih1[r] + bhh1[r];
    }
}

// ---------- persistent two-layer pipelined LSTM ----------
// blocks [0,NA): layer 0.  Each WG owns 16 h-elements; wave owns 2 elements (8 gate rows).
// blocks [NA,NWG): layer 1. Each WG owns 8 h-elements; wave owns 1 element (4 rows, K=2048).
__global__ __launch_bounds__(512, 2) void lstm_persistent(
    const float* __restrict__ inputs, const float* __restrict__ Whh0,
    const float* __restrict__ Wih1, const float* __restrict__ Whh1,
    const float* __restrict__ Wout, int* flags, float* h0r, float* h1r,
    const float* __restrict__ U, const float* __restrict__ V, const float* __restrict__ B1,
    float* part) {
    __shared__ float lds[8];
    const int tid = threadIdx.x;
    const int wv = tid >> 6;
    const int lane = tid & 63;
    const int wg = blockIdx.x;
    int* abortf = flags + 191 * FSTR + 8;

    if (wg < NA) {
        // ---- layer 0 ----
        const int base_e = wg * 16 + wv * 2;
        float4 w[8][4];   // 8 rows x 16 K-elems, rows ordered r = j*4 + g
        float uu[2][4], vv[2][4];
#pragma unroll
        for (int j = 0; j < 2; ++j)
#pragma unroll
            for (int g = 0; g < 4; ++g) {
                const int row = g * HDIM + base_e + j;
                const float4* p = (const float4*)(Whh0 + (size_t)row * HDIM + lane * 16);
                w[j * 4 + g][0] = p[0]; w[j * 4 + g][1] = p[1];
                w[j * 4 + g][2] = p[2]; w[j * 4 + g][3] = p[3];
                uu[j][g] = U[row];
                vv[j][g] = V[row];
            }
        float c0 = 0.f, c1 = 0.f;
        for (int p = 0; p <= T_STEPS; ++p) {
            if (p < T_STEPS) {
                const float* hsrc = h0r + ((p + 1) & 1) * HDIM;   // h0[p-1]
                const float4* hp = (const float4*)(hsrc + lane * 16);
                float4 hv0 = hp[0], hv1 = hp[1], hv2 = hp[2], hv3 = hp[3];
                float acc[8];
#pragma unroll
                for (int r = 0; r < 8; ++r)
                    acc[r] = dot4(w[r][0], hv0) + dot4(w[r][1], hv1) +
                             dot4(w[r][2], hv2) + dot4(w[r][3], hv3);
#pragma unroll
                for (int r = 0; r < 8; ++r) acc[r] = wred(acc[r]);
                const float st = inputs[p];
                // element j=0 (all lanes compute; lane 0 stores)
                float gi = acc[0] + st * uu[0][0] + vv[0][0];
                float gf = acc[1] + st * uu[0][1] + vv[0][1];
                float gg = acc[2] + st * uu[0][2] + vv[0][2];
                float go = acc[3] + st * uu[0][3] + vv[0][3];
                float cn0 = sigm(gf) * c0 + sigm(gi) * tanhf(gg);
                float hn0 = sigm(go) * tanhf(cn0);
                c0 = cn0;
                // element j=1
                gi = acc[4] + st * uu[1][0] + vv[1][0];
                gf = acc[5] + st * uu[1][1] + vv[1][1];
                gg = acc[6] + st * uu[1][2] + vv[1][2];
                go = acc[7] + st * uu[1][3] + vv[1][3];
                float cn1 = sigm(gf) * c1 + sigm(gi) * tanhf(gg);
                float hn1 = sigm(go) * tanhf(cn1);
                c1 = cn1;
                if (lane < 2)
                    h0r[(p & 1) * HDIM + base_e + lane] = (lane == 0) ? hn0 : hn1;
            }
            barrier_phase(flags, abortf, p + 1, tid, wv, lane, wg);
        }
    } else {
        // ---- layer 1 (one step behind) ----
        const int wb = wg - NA;
        const int e = wb * 8 + wv;
        const int kof = (lane & 31) * 32;
        const float* wsrc = (lane < 32) ? Wih1 : Whh1;   // K = [h0 ; h1prev]
        float4 w[4][8];   // 4 gate rows x 32 K-elems
        float bb[4];
#pragma unroll
        for (int g = 0; g < 4; ++g) {
            const int row = g * HDIM + e;
            const float4* p = (const float4*)(wsrc + (size_t)row * HDIM + kof);
#pragma unroll
            for (int jj = 0; jj < 8; ++jj) w[g][jj] = p[jj];
            bb[g] = B1[row];
        }
        const float woute = Wout[e];
        float c1s = 0.f;
        for (int p = 0; p <= T_STEPS; ++p) {
            if (p >= 1) {   // computes step t = p-1
                const float* hsrc = (lane < 32) ? (h0r + ((p + 1) & 1) * HDIM)   // h0[p-1]
                                                : (h1r + (p & 1) * HDIM);        // h1[p-2]
                const float4* hp = (const float4*)(hsrc + kof);
                float4 hv[8];
#pragma unroll
                for (int jj = 0; jj < 8; ++jj) hv[jj] = hp[jj];
                float acc[4];
#pragma unroll
                for (int g = 0; g < 4; ++g) {
                    float a = 0.f;
#pragma unroll
                    for (int jj = 0; jj < 8; ++jj) a += dot4(w[g][jj], hv[jj]);
                    acc[g] = a;
                }
#pragma unroll
                for (int g = 0; g < 4; ++g) acc[g] = wred(acc[g]);
                const float gi = acc[0] + bb[0];
                const float gf = acc[1] + bb[1];
                const float gg = acc[2] + bb[2];
                const float go = acc[3] + bb[3];
                const float cn = sigm(gf) * c1s + sigm(gi) * tanhf(gg);
                const float hn = sigm(go) * tanhf(cn);
                c1s = cn;
                if (lane == 0) {
                    h1r[((p + 1) & 1) * HDIM + e] = hn;   // slot (p-1)&1
                    lds[wv] = woute * hn;
                }
            }
            __syncthreads();
            if (tid == 0 && p >= 1) {
                float s = lds[0] + lds[1] + lds[2] + lds[3] +
                          lds[4] + lds[5] + lds[6] + lds[7];
                atomicAdd(&part[(size_t)(p - 1) * 8 + (wb >> 4)], s);
            }
            barrier_phase(flags, abortf, p + 1, tid, wv, lane, wg);
        }
    }
}

// ---------- output projection: out[t] = b_out + sum_seg part[t][seg] ----------
__global__ void lstm_finalize(const float* __restrict__ part, const float* __restrict__ bout,
                              float* __restrict__ out) {
    const int t = blockIdx.x * 256 + threadIdx.x;
    if (t < T_STEPS) {
        float s = bout[0];
#pragma unroll
        for (int i = 0; i < 8; ++i) s += part[(size_t)t * 8 + i];
        out[t] = s;
    }
}

extern "C" void kernel_launch(void* const* d_in, const int* in_sizes, int n_in,
                              void* d_out, int out_size, void* d_ws, size_t ws_size,
                              hipStream_t stream) {
    const float* inputs = (const float*)d_in[0];
    const float* Win  = (const float*)d_in[1];
    const float* bin  = (const float*)d_in[2];
    const float* Wih0 = (const float*)d_in[3];
    const float* Whh0 = (const float*)d_in[4];
    const float* bih0 = (const float*)d_in[5];
    const float* bhh0 = (const float*)d_in[6];
    const float* Wih1 = (const float*)d_in[7];
    const float* Whh1 = (const float*)d_in[8];
    const float* bih1 = (const float*)d_in[9];
    const float* bhh1 = (const float*)d_in[10];
    const float* Wout = (const float*)d_in[11];
    const float* bout = (const float*)d_in[12];

    char* ws = (char*)d_ws;
    int*   flags = (int*)ws;                  // 192*16 ints = 12288 B (abort at int 3064)
    float* h0r   = (float*)(ws + 12288);      // 2*1024 f = 8192 B
    float* h1r   = (float*)(ws + 20480);      // 8192 B
    float* U     = (float*)(ws + 28672);      // 4096 f
    float* V     = U + 4096;                  // 4096 f
    float* B1    = V + 4096;                  // 4096 f  (ends at 77824)
    float* part  = (float*)(ws + 77824);      // T*8 f = 262144 B

    if (ws_size < (size_t)(77824 + 262144)) return;   // loud failure if ws too small

    hipMemsetAsync(ws, 0, 28672, stream);             // flags + rings (+abort)
    hipMemsetAsync(ws + 77824, 0, 262144, stream);    // output partials

    lstm_prologue<<<1024, 256, 0, stream>>>(Wih0, Win, bin, bih0, bhh0, bih1, bhh1, U, V, B1);
    lstm_persistent<<<NWG, 512, 0, stream>>>(inputs, Whh0, Wih1, Whh1, Wout,
                                             flags, h0r, h1r, U, V, B1, part);
    lstm_finalize<<<(T_STEPS + 255) / 256, 256, 0, stream>>>(part, bout, (float*)d_out);
}

// Round 2
// 37984.027 us; speedup vs baseline: 2.1765x; 2.1765x over previous
//
#include <hip/hip_runtime.h>

#define T_STEPS 8192
#define HDIM 1024
#define NA 64            // layer-0 workgroups
#define NB 128           // layer-1 workgroups
#define NWG (NA + NB)
#define FSTR 4           // flag stride in ints (16B)

// ---------- helpers ----------
__device__ __forceinline__ float wred(float v) {
#pragma unroll
    for (int s = 32; s >= 1; s >>= 1) v += __shfl_xor(v, s, 64);
    return v;
}
__device__ __forceinline__ float sigm(float x) { return 1.0f / (1.0f + expf(-x)); }

// Coherent (L2-bypassing, device-scope) scalar accesses: sc0 sc1 forces the
// access to the L3 coherence point, so no buffer_wbl2/buffer_inv fences needed.
__device__ __forceinline__ void st_coh_i32(int* p, int v) {
    asm volatile("global_store_dword %0, %1, off sc0 sc1" :: "v"(p), "v"(v) : "memory");
}
__device__ __forceinline__ void st_coh_f32(float* p, float v) {
    asm volatile("global_store_dword %0, %1, off sc0 sc1" :: "v"(p), "v"(v) : "memory");
}

// Poll read: 3 flag lines (this lane's 3 of 192 WGs) + abort flag, one batch.
__device__ __forceinline__ void ld_flags4(const int* fp, const int* ap,
                                          int& f0, int& f1, int& f2, int& ab) {
    asm volatile(
        "global_load_dword %0, %4, off sc0 sc1\n\t"
        "global_load_dword %1, %4, off offset:1024 sc0 sc1\n\t"
        "global_load_dword %2, %4, off offset:2048 sc0 sc1\n\t"
        "global_load_dword %3, %5, off sc0 sc1\n\t"
        "s_waitcnt vmcnt(0)"
        : "=&v"(f0), "=&v"(f1), "=&v"(f2), "=&v"(ab)
        : "v"(fp), "v"(ap)
        : "memory");
}

// 16 coherent dword loads, stride 256 B (layer 0: lane owns elements lane+64j).
__device__ __forceinline__ void ld_h16_s256(const float* p, float* h) {
    asm volatile(
        "global_load_dword %0, %16, off sc0 sc1\n\t"
        "global_load_dword %1, %16, off offset:256 sc0 sc1\n\t"
        "global_load_dword %2, %16, off offset:512 sc0 sc1\n\t"
        "global_load_dword %3, %16, off offset:768 sc0 sc1\n\t"
        "global_load_dword %4, %16, off offset:1024 sc0 sc1\n\t"
        "global_load_dword %5, %16, off offset:1280 sc0 sc1\n\t"
        "global_load_dword %6, %16, off offset:1536 sc0 sc1\n\t"
        "global_load_dword %7, %16, off offset:1792 sc0 sc1\n\t"
        "global_load_dword %8, %16, off offset:2048 sc0 sc1\n\t"
        "global_load_dword %9, %16, off offset:2304 sc0 sc1\n\t"
        "global_load_dword %10, %16, off offset:2560 sc0 sc1\n\t"
        "global_load_dword %11, %16, off offset:2816 sc0 sc1\n\t"
        "global_load_dword %12, %16, off offset:3072 sc0 sc1\n\t"
        "global_load_dword %13, %16, off offset:3328 sc0 sc1\n\t"
        "global_load_dword %14, %16, off offset:3584 sc0 sc1\n\t"
        "global_load_dword %15, %16, off offset:3840 sc0 sc1\n\t"
        "s_waitcnt vmcnt(0)"
        : "=&v"(h[0]), "=&v"(h[1]), "=&v"(h[2]), "=&v"(h[3]),
          "=&v"(h[4]), "=&v"(h[5]), "=&v"(h[6]), "=&v"(h[7]),
          "=&v"(h[8]), "=&v"(h[9]), "=&v"(h[10]), "=&v"(h[11]),
          "=&v"(h[12]), "=&v"(h[13]), "=&v"(h[14]), "=&v"(h[15])
        : "v"(p)
        : "memory");
}

// 16 coherent dword loads, stride 128 B, first half (no wait).
__device__ __forceinline__ void ld_h16_s128_a(const float* p, float* h) {
    asm volatile(
        "global_load_dword %0, %16, off sc0 sc1\n\t"
        "global_load_dword %1, %16, off offset:128 sc0 sc1\n\t"
        "global_load_dword %2, %16, off offset:256 sc0 sc1\n\t"
        "global_load_dword %3, %16, off offset:384 sc0 sc1\n\t"
        "global_load_dword %4, %16, off offset:512 sc0 sc1\n\t"
        "global_load_dword %5, %16, off offset:640 sc0 sc1\n\t"
        "global_load_dword %6, %16, off offset:768 sc0 sc1\n\t"
        "global_load_dword %7, %16, off offset:896 sc0 sc1\n\t"
        "global_load_dword %8, %16, off offset:1024 sc0 sc1\n\t"
        "global_load_dword %9, %16, off offset:1152 sc0 sc1\n\t"
        "global_load_dword %10, %16, off offset:1280 sc0 sc1\n\t"
        "global_load_dword %11, %16, off offset:1408 sc0 sc1\n\t"
        "global_load_dword %12, %16, off offset:1536 sc0 sc1\n\t"
        "global_load_dword %13, %16, off offset:1664 sc0 sc1\n\t"
        "global_load_dword %14, %16, off offset:1792 sc0 sc1\n\t"
        "global_load_dword %15, %16, off offset:1920 sc0 sc1\n\t"
        : "=&v"(h[0]), "=&v"(h[1]), "=&v"(h[2]), "=&v"(h[3]),
          "=&v"(h[4]), "=&v"(h[5]), "=&v"(h[6]), "=&v"(h[7]),
          "=&v"(h[8]), "=&v"(h[9]), "=&v"(h[10]), "=&v"(h[11]),
          "=&v"(h[12]), "=&v"(h[13]), "=&v"(h[14]), "=&v"(h[15])
        : "v"(p)
        : "memory");
}

// second half (offsets 2048..3968) + drain everything.
__device__ __forceinline__ void ld_h16_s128_b(const float* p, float* h) {
    asm volatile(
        "global_load_dword %0, %16, off offset:2048 sc0 sc1\n\t"
        "global_load_dword %1, %16, off offset:2176 sc0 sc1\n\t"
        "global_load_dword %2, %16, off offset:2304 sc0 sc1\n\t"
        "global_load_dword %3, %16, off offset:2432 sc0 sc1\n\t"
        "global_load_dword %4, %16, off offset:2560 sc0 sc1\n\t"
        "global_load_dword %5, %16, off offset:2688 sc0 sc1\n\t"
        "global_load_dword %6, %16, off offset:2816 sc0 sc1\n\t"
        "global_load_dword %7, %16, off offset:2944 sc0 sc1\n\t"
        "global_load_dword %8, %16, off offset:3072 sc0 sc1\n\t"
        "global_load_dword %9, %16, off offset:3200 sc0 sc1\n\t"
        "global_load_dword %10, %16, off offset:3328 sc0 sc1\n\t"
        "global_load_dword %11, %16, off offset:3456 sc0 sc1\n\t"
        "global_load_dword %12, %16, off offset:3584 sc0 sc1\n\t"
        "global_load_dword %13, %16, off offset:3712 sc0 sc1\n\t"
        "global_load_dword %14, %16, off offset:3840 sc0 sc1\n\t"
        "global_load_dword %15, %16, off offset:3968 sc0 sc1\n\t"
        "s_waitcnt vmcnt(0)"
        : "=&v"(h[0]), "=&v"(h[1]), "=&v"(h[2]), "=&v"(h[3]),
          "=&v"(h[4]), "=&v"(h[5]), "=&v"(h[6]), "=&v"(h[7]),
          "=&v"(h[8]), "=&v"(h[9]), "=&v"(h[10]), "=&v"(h[11]),
          "=&v"(h[12]), "=&v"(h[13]), "=&v"(h[14]), "=&v"(h[15])
        : "v"(p)
        : "memory");
}

__device__ __forceinline__ void poll_flags(int* flags, int target, int lane) {
    const int* fp = flags + lane * FSTR;
    int* ap = flags + NWG * FSTR;   // abort int
    long it = 0;
    for (;;) {
        int f0, f1, f2, ab;
        ld_flags4(fp, ap, f0, f1, f2, ab);
        int ok = (f0 >= target) && (f1 >= target) && (f2 >= target);
        if (__all(ok || (ab != 0))) break;
        if (++it > 50000000L)   // deadlock valve: convert hang -> fast wrong exit
            st_coh_i32(ap, 1);
    }
}

// ---------- prologue: U = Wih0*Win, V = Wih0*bin + bih0 + bhh0, B1 = bih1 + bhh1 ----------
__global__ void lstm_prologue(const float* __restrict__ Wih0, const float* __restrict__ Win,
                              const float* __restrict__ bin, const float* __restrict__ bih0,
                              const float* __restrict__ bhh0, const float* __restrict__ bih1,
                              const float* __restrict__ bhh1,
                              float* __restrict__ U, float* __restrict__ V, float* __restrict__ B1) {
    const int wv = threadIdx.x >> 6, lane = threadIdx.x & 63;
    const int r = blockIdx.x * 4 + wv;
    const float* wp = Wih0 + (size_t)r * HDIM;
    float au = 0.f, av = 0.f;
#pragma unroll
    for (int j = 0; j < 16; ++j) {
        float wj = wp[lane + 64 * j];
        au += wj * Win[lane + 64 * j];
        av += wj * bin[lane + 64 * j];
    }
    au = wred(au);
    av = wred(av);
    if (lane == 0) {
        U[r] = au;
        V[r] = av + bih0[r] + bhh0[r];
        B1[r] = bih1[r] + bhh1[r];
    }
}

// ---------- persistent two-layer pipelined LSTM ----------
__global__ __launch_bounds__(512, 2) void lstm_persistent(
    const float* __restrict__ inputs, const float* __restrict__ Whh0,
    const float* __restrict__ Wih1, const float* __restrict__ Whh1,
    const float* __restrict__ Wout, int* flags, float* h0r, float* h1r,
    const float* __restrict__ U, const float* __restrict__ V, const float* __restrict__ B1,
    float* part) {
    __shared__ float lds[2][8];
    const int tid = threadIdx.x;
    const int wv = tid >> 6;
    const int lane = tid & 63;
    const int wg = blockIdx.x;

    if (wg < NA) {
        // ---- layer 0: WG owns 16 h-elements, wave owns 2 (8 gate rows). ----
        // lane owns K-elements {lane + 64j}, j=0..15  (coalesced sc1 dword loads)
        const int base_e = wg * 16 + wv * 2;
        float w[8][16];
        float uu[2][4], vv[2][4];
#pragma unroll
        for (int j = 0; j < 2; ++j)
#pragma unroll
            for (int g = 0; g < 4; ++g) {
                const int row = g * HDIM + base_e + j;
                const float* p = Whh0 + (size_t)row * HDIM;
#pragma unroll
                for (int k = 0; k < 16; ++k) w[j * 4 + g][k] = p[lane + 64 * k];
                uu[j][g] = U[row];
                vv[j][g] = V[row];
            }
        float c0 = 0.f, c1 = 0.f;
        for (int p = 0; p <= T_STEPS; ++p) {
            if (p < T_STEPS) {
                const float* hsrc = h0r + ((p + 1) & 1) * HDIM + lane;   // h0[p-1]
                float hv[16];
                ld_h16_s256(hsrc, hv);
                float acc[8];
#pragma unroll
                for (int r = 0; r < 8; ++r) {
                    float a = 0.f;
#pragma unroll
                    for (int k = 0; k < 16; ++k) a += w[r][k] * hv[k];
                    acc[r] = a;
                }
#pragma unroll
                for (int r = 0; r < 8; ++r) acc[r] = wred(acc[r]);
                const float st = inputs[p];
                float gi = acc[0] + st * uu[0][0] + vv[0][0];
                float gf = acc[1] + st * uu[0][1] + vv[0][1];
                float gg = acc[2] + st * uu[0][2] + vv[0][2];
                float go = acc[3] + st * uu[0][3] + vv[0][3];
                float cn0 = sigm(gf) * c0 + sigm(gi) * tanhf(gg);
                float hn0 = sigm(go) * tanhf(cn0);
                c0 = cn0;
                gi = acc[4] + st * uu[1][0] + vv[1][0];
                gf = acc[5] + st * uu[1][1] + vv[1][1];
                gg = acc[6] + st * uu[1][2] + vv[1][2];
                go = acc[7] + st * uu[1][3] + vv[1][3];
                float cn1 = sigm(gf) * c1 + sigm(gi) * tanhf(gg);
                float hn1 = sigm(go) * tanhf(cn1);
                c1 = cn1;
                if (lane < 2)
                    st_coh_f32(h0r + (p & 1) * HDIM + base_e + lane, lane == 0 ? hn0 : hn1);
            }
            asm volatile("s_waitcnt vmcnt(0)" ::: "memory");
            __syncthreads();
            if (tid == 0) st_coh_i32(flags + wg * FSTR, p + 1);
            if (wv == 0) poll_flags(flags, p + 1, lane);
            __syncthreads();
        }
    } else {
        // ---- layer 1 (one step behind): WG owns 8 h-elements, wave owns 1 (4 rows, K=2048). ----
        // lane<32: Wih1 half (h0), lane>=32: Whh1 half (h1prev); lane owns {hl + 32j}, j=0..31.
        const int wb = wg - NA;
        const int e = wb * 8 + wv;
        const int hl = lane & 31;
        const float* wsrc = (lane < 32) ? Wih1 : Whh1;
        float w[4][32];
        float bb[4];
#pragma unroll
        for (int g = 0; g < 4; ++g) {
            const int row = g * HDIM + e;
            const float* p = wsrc + (size_t)row * HDIM;
#pragma unroll
            for (int k = 0; k < 32; ++k) w[g][k] = p[hl + 32 * k];
            bb[g] = B1[row];
        }
        const float woute = Wout[e];
        float c1s = 0.f;
        for (int p = 0; p <= T_STEPS; ++p) {
            // deferred output-partial store for step t=p-2 (off the flag critical path)
            if (tid == 0 && p >= 2) {
                float s = lds[p & 1][0] + lds[p & 1][1] + lds[p & 1][2] + lds[p & 1][3] +
                          lds[p & 1][4] + lds[p & 1][5] + lds[p & 1][6] + lds[p & 1][7];
                part[(size_t)(p - 2) * 128 + wb] = s;   // plain store, read by finalize
            }
            if (p >= 1) {   // computes step t = p-1
                const float* hb = (lane < 32) ? (h0r + ((p + 1) & 1) * HDIM + hl)   // h0[p-1]
                                              : (h1r + (p & 1) * HDIM + hl);        // h1[p-2]
                float hv[32];
                ld_h16_s128_a(hb, hv);
                ld_h16_s128_b(hb, hv + 16);
                float acc[4];
#pragma unroll
                for (int g = 0; g < 4; ++g) {
                    float a = 0.f;
#pragma unroll
                    for (int k = 0; k < 32; ++k) a += w[g][k] * hv[k];
                    acc[g] = a;
                }
#pragma unroll
                for (int g = 0; g < 4; ++g) acc[g] = wred(acc[g]);
                const float gi = acc[0] + bb[0];
                const float gf = acc[1] + bb[1];
                const float gg = acc[2] + bb[2];
                const float go = acc[3] + bb[3];
                const float cn = sigm(gf) * c1s + sigm(gi) * tanhf(gg);
                const float hn = sigm(go) * tanhf(cn);
                c1s = cn;
                if (lane == 0) {
                    st_coh_f32(h1r + ((p + 1) & 1) * HDIM + e, hn);   // slot (p-1)&1
                    lds[(p - 1) & 1][wv] = woute * hn;
                }
            }
            asm volatile("s_waitcnt vmcnt(0)" ::: "memory");
            __syncthreads();
            if (tid == 0) st_coh_i32(flags + wg * FSTR, p + 1);
            if (wv == 0) poll_flags(flags, p + 1, lane);
            __syncthreads();
        }
        // epilogue: partial for step T-1 (computed at phase T)
        if (tid == 0) {
            const int q = (T_STEPS - 1) & 1;
            float s = lds[q][0] + lds[q][1] + lds[q][2] + lds[q][3] +
                      lds[q][4] + lds[q][5] + lds[q][6] + lds[q][7];
            part[(size_t)(T_STEPS - 1) * 128 + wb] = s;
        }
    }
}

// ---------- output projection: out[t] = b_out + sum_wb part[t][wb] ----------
__global__ void lstm_finalize(const float* __restrict__ part, const float* __restrict__ bout,
                              float* __restrict__ out) {
    const int t = blockIdx.x * 256 + threadIdx.x;
    if (t < T_STEPS) {
        const float4* p4 = (const float4*)(part + (size_t)t * 128);
        float s = bout[0];
#pragma unroll
        for (int i = 0; i < 32; ++i) {
            float4 v = p4[i];
            s += v.x + v.y + v.z + v.w;
        }
        out[t] = s;
    }
}

extern "C" void kernel_launch(void* const* d_in, const int* in_sizes, int n_in,
                              void* d_out, int out_size, void* d_ws, size_t ws_size,
                              hipStream_t stream) {
    const float* inputs = (const float*)d_in[0];
    const float* Win  = (const float*)d_in[1];
    const float* bin  = (const float*)d_in[2];
    const float* Wih0 = (const float*)d_in[3];
    const float* Whh0 = (const float*)d_in[4];
    const float* bih0 = (const float*)d_in[5];
    const float* bhh0 = (const float*)d_in[6];
    const float* Wih1 = (const float*)d_in[7];
    const float* Whh1 = (const float*)d_in[8];
    const float* bih1 = (const float*)d_in[9];
    const float* bhh1 = (const float*)d_in[10];
    const float* Wout = (const float*)d_in[11];
    const float* bout = (const float*)d_in[12];

    char* ws = (char*)d_ws;
    int*   flags = (int*)ws;                  // 193*16 B (abort at int NWG*FSTR), pad to 4096
    float* h0r   = (float*)(ws + 4096);       // 2*1024 f = 8192 B
    float* h1r   = (float*)(ws + 12288);      // 8192 B
    float* U     = (float*)(ws + 20480);      // 4096 f = 16384 B
    float* V     = (float*)(ws + 36864);      // 16384 B
    float* B1    = (float*)(ws + 53248);      // 16384 B (ends 69632)
    float* part  = (float*)(ws + 69632);      // T*128 f = 4 MB

    if (ws_size < (size_t)(69632 + (size_t)T_STEPS * 128 * 4)) return;

    hipMemsetAsync(ws, 0, 20480, stream);     // flags + abort + both h rings

    lstm_prologue<<<1024, 256, 0, stream>>>(Wih0, Win, bin, bih0, bhh0, bih1, bhh1, U, V, B1);
    lstm_persistent<<<NWG, 512, 0, stream>>>(inputs, Whh0, Wih1, Whh1, Wout,
                                             flags, h0r, h1r, U, V, B1, part);
    lstm_finalize<<<(T_STEPS + 255) / 256, 256, 0, stream>>>(part, bout, (float*)d_out);
}